// Round 16
// baseline (121.280 us; speedup 1.0000x reference)
//
#include <hip/hip_runtime.h>

typedef short sh8 __attribute__((ext_vector_type(8)));   // 8 bf16
typedef float fx4 __attribute__((ext_vector_type(4)));   // MFMA accumulator
typedef float fl4 __attribute__((ext_vector_type(4)));   // ext-vector float4
typedef unsigned short us4 __attribute__((ext_vector_type(4)));

__device__ __forceinline__ unsigned short f2bf(float f) {
    union { float f; unsigned u; } v; v.f = f;
    unsigned r = v.u + 0x7FFFu + ((v.u >> 16) & 1u);   // RNE
    return (unsigned short)(r >> 16);
}
__device__ __forceinline__ float EX2(float x) { return __builtin_amdgcn_exp2f(x); }
__device__ __forceinline__ unsigned cvtpk(float a, float b) {   // 2xf32 -> packed bf16 (RNE)
    unsigned r;
    asm("v_cvt_pk_bf16_f32 %0, %1, %2" : "=v"(r) : "v"(a), "v"(b));
    return r;
}
// async global->LDS, 16B per lane; LDS dest = wave-uniform base + lane*16
__device__ __forceinline__ void gl16(const unsigned short* g, unsigned short* l) {
    __builtin_amdgcn_global_load_lds(
        (const __attribute__((address_space(1))) unsigned int*)g,
        (__attribute__((address_space(3))) unsigned int*)l, 16, 0, 0);
}

// ---------------- prep: cvt inputs + transpose weights + pack mask (r9-proven) ------------
__global__ __launch_bounds__(256) void prep(const float* __restrict__ x0,
                                            const float* __restrict__ x1,
                                            const float* __restrict__ x2,
                                            const float* __restrict__ w0,
                                            const float* __restrict__ w1,
                                            const float* __restrict__ w2,
                                            const float* __restrict__ w3,
                                            const int* __restrict__ mask,
                                            unsigned short* __restrict__ in_bf,
                                            unsigned short* __restrict__ wt,
                                            unsigned long long* __restrict__ mp2) {
    __shared__ float tw[32][33];
    const int bid = blockIdx.x, tid = threadIdx.x;
    if (bid < 1536) {                               // cvt: 3 inputs x 512 blocks
        const int z = bid >> 9, xb = bid & 511;
        const float* src = z == 0 ? x0 : (z == 1 ? x1 : x2);
        unsigned short* dst = in_bf + (size_t)z * 2097152;
        for (int i = xb * 256 + tid; i < 524288; i += 131072) {
            float4 v = ((const float4*)src)[i];
            ushort4 o;
            o.x = f2bf(v.x); o.y = f2bf(v.y); o.z = f2bf(v.z); o.w = f2bf(v.w);
            ((ushort4*)dst)[i] = o;
        }
    } else if (bid < 2560) {                        // transpose_w: 4 x (16x16) blocks
        const int t = bid - 1536;
        const int z = t >> 8, bx = t & 15, by = (t >> 4) & 15;
        const float* W = z == 0 ? w0 : z == 1 ? w1 : z == 2 ? w2 : w3;
        unsigned short* Wt = wt + (size_t)z * 262144;
        const int tx = tid & 31, ty = tid >> 5;
        #pragma unroll
        for (int i = 0; i < 4; ++i)
            tw[ty + i * 8][tx] = W[(size_t)(by * 32 + ty + i * 8) * 512 + bx * 32 + tx];
        __syncthreads();
        #pragma unroll
        for (int i = 0; i < 4; ++i)
            Wt[(size_t)(bx * 32 + ty + i * 8) * 512 + by * 32 + tx] = f2bf(tw[tx][ty + i * 8]);
    } else {                                        // pack_mask: 16 blocks (2 b x 8)
        const int p = bid - 2560;
        const int b = p >> 3, k = (p & 7) * 256 + tid;
        int v = mask[(size_t)b * 4194304 + k];
        unsigned long long bal = __ballot(v != 0);
        if ((tid & 63) == 0) mp2[b * 32 + (k >> 6)] = bal;
    }
}

// ---------------- GEMM: C[4096,512] = A_bf16 @ Wt^T + bias (r9-proven) ----------------
template <int MODE>
__global__ __launch_bounds__(256) void gemm_k(const unsigned short* __restrict__ Aall,
                                              const unsigned short* __restrict__ Wtall,
                                              const float* __restrict__ b0,
                                              const float* __restrict__ b1,
                                              const float* __restrict__ b2,
                                              void* __restrict__ outp,
                                              unsigned short* __restrict__ VtB) {
    const int z = blockIdx.z;
    const unsigned short* A  = Aall  + (size_t)z * (4096 * 512);
    const unsigned short* Bt = Wtall + (size_t)z * (512 * 512);
    const float* bias = (MODE == 0) ? (z == 0 ? b0 : (z == 1 ? b1 : b2)) : b0;

    __shared__ __align__(16) unsigned short As[128 * 64];   // XOR-swizzled chunks
    __shared__ __align__(16) unsigned short Bs[64 * 64];

    const int tid = threadIdx.x;
    const int wid = tid >> 6, lane = tid & 63, lr = lane & 15, lg = lane >> 4;
    const int wr = wid >> 1, wc = wid & 1;
    const int mblk = blockIdx.x * 128, nblk = blockIdx.y * 64;
    const int r7 = lr & 7;

    fx4 acc[4][2];
    #pragma unroll
    for (int mf = 0; mf < 4; ++mf)
        #pragma unroll
        for (int nf = 0; nf < 2; ++nf)
            #pragma unroll
            for (int j = 0; j < 4; ++j) acc[mf][nf][j] = 0.f;

    for (int kt = 0; kt < 8; ++kt) {
        __syncthreads();                         // WAR
        #pragma unroll
        for (int g = 0; g < 4; ++g) {            // A: 1024 chunks, 256/wave
            int ci = wid * 256 + g * 64 + lane;
            int r = ci >> 3, c = (ci & 7) ^ (r & 7);
            gl16(A + (size_t)(mblk + r) * 512 + kt * 64 + c * 8, &As[(wid * 256 + g * 64) * 8]);
        }
        #pragma unroll
        for (int g = 0; g < 2; ++g) {            // B: 512 chunks, 128/wave
            int ci = wid * 128 + g * 64 + lane;
            int r = ci >> 3, c = (ci & 7) ^ (r & 7);
            gl16(Bt + (size_t)(nblk + r) * 512 + kt * 64 + c * 8, &Bs[(wid * 128 + g * 64) * 8]);
        }
        __syncthreads();                         // RAW (compiler drains vmcnt)
        #pragma unroll
        for (int d = 0; d < 2; ++d) {
            sh8 af[4], bf[2];
            #pragma unroll
            for (int mf = 0; mf < 4; ++mf)
                af[mf] = *(const sh8*)&As[(wr * 64 + mf * 16 + lr) * 64 + (((d * 4 + lg) ^ r7) * 8)];
            #pragma unroll
            for (int nf = 0; nf < 2; ++nf)
                bf[nf] = *(const sh8*)&Bs[(wc * 32 + nf * 16 + lr) * 64 + (((d * 4 + lg) ^ r7) * 8)];
            #pragma unroll
            for (int mf = 0; mf < 4; ++mf)
                #pragma unroll
                for (int nf = 0; nf < 2; ++nf)
                    acc[mf][nf] = __builtin_amdgcn_mfma_f32_16x16x32_bf16(af[mf], bf[nf], acc[mf][nf], 0, 0, 0);
        }
    }

    if (MODE == 0 && z == 1) {
        // V: write transposed only -> VtB[(b*8+h)*64 + dd][lq]
        #pragma unroll
        for (int nf = 0; nf < 2; ++nf) {
            int n = nblk + wc * 32 + nf * 16 + lr;
            float bv = bias[n];
            int h = n >> 6, dd = n & 63;
            #pragma unroll
            for (int mf = 0; mf < 4; ++mf) {
                int m0 = mblk + wr * 64 + mf * 16 + lg * 4;
                int bb = m0 >> 11, lq = m0 & 2047;
                ushort4 o;
                o.x = f2bf(acc[mf][nf][0] + bv);
                o.y = f2bf(acc[mf][nf][1] + bv);
                o.z = f2bf(acc[mf][nf][2] + bv);
                o.w = f2bf(acc[mf][nf][3] + bv);
                *(ushort4*)(VtB + ((size_t)(bb * 8 + h) * 64 + dd) * 2048 + lq) = o;
            }
        }
    } else {
        #pragma unroll
        for (int nf = 0; nf < 2; ++nf) {
            int n = nblk + wc * 32 + nf * 16 + lr;
            float bv = bias[n];
            #pragma unroll
            for (int mf = 0; mf < 4; ++mf) {
                #pragma unroll
                for (int j = 0; j < 4; ++j) {
                    int m = mblk + wr * 64 + mf * 16 + lg * 4 + j;
                    float val = acc[mf][nf][j] + bv;
                    if (MODE == 0) {
                        if (z == 2) val *= 0.180336880f;   // (1/sqrt(64))*log2e: exp2 domain
                        int bb = m >> 11, lq = m & 2047, h = n >> 6, dd = n & 63;
                        ((unsigned short*)outp)[(size_t)(((z * 2 + bb) * 8 + h) * 2048 + lq) * 64 + dd] = f2bf(val);
                    } else {
                        ((float*)outp)[(size_t)m * 512 + n] = val;
                    }
                }
            }
        }
    }
}

// ---------------- fused attention: quad-A (4 tiles/barrier) + pair-B pipeline -------------
__device__ __forceinline__ void stage_k1(const unsigned short* Kg, unsigned short* sK,
                                         int t, int w, int lane) {
    #pragma unroll
    for (int g = 0; g < 2; ++g) {
        int ci = w * 128 + g * 64 + lane;
        int r = ci >> 3, c = (ci & 7) ^ (r & 7);
        gl16(Kg + (size_t)(t * 64 + r) * 64 + c * 8, sK + (w * 128 + g * 64) * 8);
    }
}
__device__ __forceinline__ void stage_kv(const unsigned short* Kg, const unsigned short* Vg,
                                         unsigned short* sK, unsigned short* sV,
                                         int t, int w, int lane) {
    #pragma unroll
    for (int g = 0; g < 2; ++g) {
        int ci = w * 128 + g * 64 + lane;
        int r = ci >> 3, c = (ci & 7) ^ (r & 7);
        gl16(Kg + (size_t)(t * 64 + r) * 64 + c * 8, sK + (w * 128 + g * 64) * 8);
        gl16(Vg + (size_t)r * 2048 + t * 64 + c * 8, sV + (w * 128 + g * 64) * 8);
    }
}

__global__ __launch_bounds__(256, 2) void attn_fused(const unsigned short* __restrict__ qkv,
                                                     const unsigned short* __restrict__ Vt,
                                                     const unsigned long long* __restrict__ mp2,
                                                     float* __restrict__ aw,
                                                     unsigned short* __restrict__ cv) {
    const int bid = blockIdx.x;
    // batch-balanced XCD swizzle: XCD c hosts bh {c, c+8} (one per batch), bijective.
    const int bh = (bid & 7) | (((bid >> 3) & 1) << 3);
    const int qb = bid >> 4;
    const int b = bh >> 3, h = bh & 7;
    const unsigned short* Kg = qkv + (size_t)bh * 131072;
    const unsigned short* Vg = Vt + (size_t)bh * 131072;    // [64 d][2048 k]
    const unsigned short* Qg = qkv + 2 * 2097152 + (size_t)bh * 131072 + (size_t)qb * 4096;

    // KR: phase A = 8-slot K ring (tile kt -> slot kt&7, 2 quads in flight);
    //     phase B = K slots 0..3 (pair ring) + V slots 4..7
    __shared__ __align__(16) unsigned short KR[8][4096];
    __shared__ __align__(16) unsigned short Pb[4096];

    const int tid = threadIdx.x, w = tid >> 6, lane = tid & 63, lr = lane & 15, lg = lane >> 4;
    const int r7 = lr & 7;
    const int q = qb * 64 + w * 16 + lr;

    sh8 qf0 = *(const sh8*)(Qg + (w * 16 + lr) * 64 + lg * 8);
    sh8 qf1 = *(const sh8*)(Qg + (w * 16 + lr) * 64 + 32 + lg * 8);
    unsigned long long mwv = (lane < 32) ? mp2[b * 32 + lane] : 0ull;

    // trailing-masked-tile count (block-uniform: mask depends only on b)
    unsigned long long bits = __ballot(mwv != 0ull);
    const int ntiles = (bits == 0ull) ? 0 : (64 - __clzll(bits));
    const int npairs = (ntiles + 1) >> 1;
    const int nquads = (ntiles + 3) >> 2;

    float* awb = aw + (size_t)bh * 4194304 + (size_t)q * 2048;

    // ---------- phase A: softmax stats (exp2 domain), 4 tiles per barrier pair ------------
    float m_ = -3e38f, l_ = 0.f;
    if (ntiles > 0) {
        asm volatile("s_waitcnt vmcnt(0)" ::: "memory");
        #pragma unroll
        for (int t = 0; t < 4; ++t)
            stage_k1(Kg, KR[t], (t < ntiles) ? t : (ntiles - 1), w, lane);
        if (nquads > 1) {
            #pragma unroll
            for (int t = 4; t < 8; ++t)
                stage_k1(Kg, KR[t], (t < ntiles) ? t : (ntiles - 1), w, lane);
        }
        for (int p = 0; p < nquads; ++p) {
            if (p >= 1 && p <= nquads - 2) {
                #pragma unroll
                for (int tt = 0; tt < 4; ++tt) {
                    int t = 4 * p + 4 + tt;
                    stage_k1(Kg, KR[t & 7], (t < ntiles) ? t : (ntiles - 1), w, lane);
                }
            }
            // outstanding: quad p (8/wave) + quad p+1 (8/wave) -> vmcnt(8) retires quad p
            if (p == nquads - 1) asm volatile("s_waitcnt vmcnt(0)" ::: "memory");
            else                 asm volatile("s_waitcnt vmcnt(8)" ::: "memory");
            asm volatile("s_barrier" ::: "memory");          // RAW: quad p staged
            #pragma unroll
            for (int tt = 0; tt < 4; ++tt) {
                const int kt = 4 * p + tt;
                unsigned long long mw = __shfl(mwv, kt, 64);
                if (mw == 0ull) continue;
                const unsigned short* KsB = KR[kt & 7];
                fx4 accs[4];
                #pragma unroll
                for (int mt = 0; mt < 4; ++mt) {
                    sh8 kf0 = *(const sh8*)&KsB[(mt * 16 + lr) * 64 + ((lg ^ r7) * 8)];
                    sh8 kf1 = *(const sh8*)&KsB[(mt * 16 + lr) * 64 + (((4 + lg) ^ r7) * 8)];
                    fx4 zz; zz[0] = 0.f; zz[1] = 0.f; zz[2] = 0.f; zz[3] = 0.f;
                    zz = __builtin_amdgcn_mfma_f32_16x16x32_bf16(kf0, qf0, zz, 0, 0, 0);
                    accs[mt] = __builtin_amdgcn_mfma_f32_16x16x32_bf16(kf1, qf1, zz, 0, 0, 0);
                }
                float sv[16], tmax = -3e38f;
                if (mw == ~0ull) {
                    #pragma unroll
                    for (int mt = 0; mt < 4; ++mt)
                        #pragma unroll
                        for (int j = 0; j < 4; ++j) {
                            float s = accs[mt][j];
                            sv[mt * 4 + j] = s; tmax = fmaxf(tmax, s);
                        }
                } else {
                    #pragma unroll
                    for (int mt = 0; mt < 4; ++mt)
                        #pragma unroll
                        for (int j = 0; j < 4; ++j) {
                            int kl = mt * 16 + lg * 4 + j;
                            bool ok = (mw >> kl) & 1ull;
                            float s = ok ? accs[mt][j] : -3e38f;
                            sv[mt * 4 + j] = s; tmax = fmaxf(tmax, s);
                        }
                }
                float mnew = fmaxf(m_, tmax);
                float ps = 0.f;
                #pragma unroll
                for (int i = 0; i < 16; ++i) ps += EX2(sv[i] - mnew);
                l_ = l_ * EX2(m_ - mnew) + ps;
                m_ = mnew;
            }
            asm volatile("s_barrier" ::: "memory");          // WAR: quad p-1 slots free
        }
    }
    // butterfly merge across lg groups -> every lane holds full-row (M, L)
    #pragma unroll
    for (int off = 16; off <= 32; off <<= 1) {
        float mo = __shfl_xor(m_, off), lo = __shfl_xor(l_, off);
        float mn = fmaxf(m_, mo);
        l_ = l_ * EX2(m_ - mn) + lo * EX2(mo - mn);
        m_ = mn;
    }
    // fold 1/L into the exponent: p = 2^(s - Mshift), Mshift = M + log2(L)
    const float Mshift = (l_ > 0.f) ? (m_ + __log2f(l_)) : 3e38f;

    // ---------- phase B: recompute S^T, write normalized aw, accumulate PV (r15 pair) -----
    fx4 acco[4];
    #pragma unroll
    for (int md = 0; md < 4; ++md) { acco[md][0] = 0.f; acco[md][1] = 0.f; acco[md][2] = 0.f; acco[md][3] = 0.f; }

    if (ntiles > 0) {
        asm volatile("s_waitcnt vmcnt(0)" ::: "memory");
        stage_kv(Kg, Vg, KR[0], KR[4], 0, w, lane);
        stage_kv(Kg, Vg, KR[1], KR[5], 1, w, lane);
        if (npairs > 1) {
            stage_kv(Kg, Vg, KR[2], KR[6], 2, w, lane);
            stage_kv(Kg, Vg, KR[3], KR[7], 3, w, lane);
        }
        for (int p = 0; p < npairs; ++p) {
            if (p >= 1 && p <= npairs - 2) {
                stage_kv(Kg, Vg, KR[(2 * p + 2) & 3], KR[4 + ((2 * p + 2) & 3)], 2 * p + 2, w, lane);
                stage_kv(Kg, Vg, KR[(2 * p + 3) & 3], KR[4 + ((2 * p + 3) & 3)], 2 * p + 3, w, lane);
            }
            // FIFO (steady): [L_p 8][S_{p-1} 8][L_{p+1} 8] -> vmcnt(16) retires L_p only.
            if (p == 0 && npairs == 1) asm volatile("s_waitcnt vmcnt(0)" ::: "memory");
            else if (p == 0 || p == npairs - 1) asm volatile("s_waitcnt vmcnt(8)" ::: "memory");
            else                                asm volatile("s_waitcnt vmcnt(16)" ::: "memory");
            asm volatile("s_barrier" ::: "memory");          // RAW

            #pragma unroll
            for (int tt = 0; tt < 2; ++tt) {
                const int kt = 2 * p + tt;
                unsigned long long mw = __shfl(mwv, kt, 64);
                const unsigned short* KsB = KR[kt & 3];
                const unsigned short* VsB = KR[4 + (kt & 3)];

                if (mw != 0ull) {
                    fx4 accs[4];
                    #pragma unroll
                    for (int mt = 0; mt < 4; ++mt) {
                        sh8 kf0 = *(const sh8*)&KsB[(mt * 16 + lr) * 64 + ((lg ^ r7) * 8)];
                        sh8 kf1 = *(const sh8*)&KsB[(mt * 16 + lr) * 64 + (((4 + lg) ^ r7) * 8)];
                        fx4 zz; zz[0] = 0.f; zz[1] = 0.f; zz[2] = 0.f; zz[3] = 0.f;
                        zz = __builtin_amdgcn_mfma_f32_16x16x32_bf16(kf0, qf0, zz, 0, 0, 0);
                        accs[mt] = __builtin_amdgcn_mfma_f32_16x16x32_bf16(kf1, qf1, zz, 0, 0, 0);
                    }
                    bool full = (mw == ~0ull);
                    #pragma unroll
                    for (int mt = 0; mt < 4; ++mt) {
                        fl4 pw;
                        #pragma unroll
                        for (int j = 0; j < 4; ++j) {
                            int kl = mt * 16 + lg * 4 + j;
                            bool ok = full || ((mw >> kl) & 1ull);
                            pw[j] = EX2((ok ? accs[mt][j] : -3e38f) - Mshift);
                        }
                        *(fl4*)(awb + kt * 64 + mt * 16 + lg * 4) = pw;
                        int sc = (mt * 2 + (lg >> 1)) ^ r7;
                        *(uint2*)&Pb[(w * 16 + lr) * 64 + sc * 8 + (lg & 1) * 4] =
                            make_uint2(cvtpk(pw[0], pw[1]), cvtpk(pw[2], pw[3]));
                    }
                    asm volatile("s_waitcnt lgkmcnt(0)" ::: "memory");   // wave-private Pb RAW
                    __builtin_amdgcn_sched_barrier(0);
                    sh8 bp0 = *(const sh8*)&Pb[(w * 16 + lr) * 64 + ((lg ^ r7) * 8)];
                    sh8 bp1 = *(const sh8*)&Pb[(w * 16 + lr) * 64 + (((4 + lg) ^ r7) * 8)];
                    #pragma unroll
                    for (int md = 0; md < 4; ++md) {
                        sh8 vf0 = *(const sh8*)&VsB[(md * 16 + lr) * 64 + ((lg ^ r7) * 8)];
                        sh8 vf1 = *(const sh8*)&VsB[(md * 16 + lr) * 64 + (((4 + lg) ^ r7) * 8)];
                        acco[md] = __builtin_amdgcn_mfma_f32_16x16x32_bf16(vf0, bp0, acco[md], 0, 0, 0);
                        acco[md] = __builtin_amdgcn_mfma_f32_16x16x32_bf16(vf1, bp1, acco[md], 0, 0, 0);
                    }
                } else {
                    fl4 z4 = {0.f, 0.f, 0.f, 0.f};
                    #pragma unroll
                    for (int mt = 0; mt < 4; ++mt)      // exactly 4 stores: keeps vmcnt accounting
                        *(fl4*)(awb + kt * 64 + mt * 16 + lg * 4) = z4;
                }
            }
            asm volatile("s_barrier" ::: "memory");          // WAR before restage
        }
    }

    // zero-fill trailing fully-masked tiles (no staging, no barriers)
    for (int kt = ntiles; kt < 32; ++kt) {
        fl4 z4 = {0.f, 0.f, 0.f, 0.f};
        #pragma unroll
        for (int mt = 0; mt < 4; ++mt)
            *(fl4*)(awb + kt * 64 + mt * 16 + lg * 4) = z4;
    }

    // epilogue: complete PV row -> cvb bf16 [4096][512]
    #pragma unroll
    for (int md = 0; md < 4; ++md) {
        uint2 o = make_uint2(cvtpk(acco[md][0], acco[md][1]), cvtpk(acco[md][2], acco[md][3]));
        *(uint2*)(cv + (size_t)(b * 2048 + q) * 512 + h * 64 + md * 16 + lg * 4) = o;
    }
}

// ---------------- launch ----------------
extern "C" void kernel_launch(void* const* d_in, const int* in_sizes, int n_in,
                              void* d_out, int out_size, void* d_ws, size_t ws_size,
                              hipStream_t stream) {
    const float* key_in   = (const float*)d_in[0];
    const float* value_in = (const float*)d_in[1];
    const float* query_in = (const float*)d_in[2];
    const float* Wk = (const float*)d_in[3];
    const float* bk = (const float*)d_in[4];
    const float* Wv = (const float*)d_in[5];
    const float* bv = (const float*)d_in[6];
    const float* Wq = (const float*)d_in[7];
    const float* bq = (const float*)d_in[8];
    const float* Wo = (const float*)d_in[9];
    const float* bo = (const float*)d_in[10];
    const int* mask = (const int*)d_in[11];

    char* ws = (char*)d_ws;
    unsigned short* in_bf = (unsigned short*)(ws);                  // 12.58M
    unsigned short* qkv   = (unsigned short*)(ws + 12582912);       // 12.58M: K slot0, Q slot2
    unsigned short* cvb   = (unsigned short*)(ws + 12582912 + 4194304); // overlays unused V slot1
    unsigned short* wt    = (unsigned short*)(ws + 25165824);       // 2.10M
    unsigned short* VtB   = (unsigned short*)(ws + 27262976);       // 4.19M
    unsigned long long* mp2 = (unsigned long long*)(ws + 31457280); // 512 B

    float* out_cv = (float*)d_out;
    float* out_aw = (float*)d_out + 2097152;

    prep<<<dim3(2576), 256, 0, stream>>>(key_in, value_in, query_in,
                                         Wk, Wv, Wq, Wo, mask, in_bf, wt, mp2);
    gemm_k<0><<<dim3(32, 8, 3), 256, 0, stream>>>(in_bf, wt, bk, bv, bq, qkv, VtB);
    attn_fused<<<dim3(512), 256, 0, stream>>>(qkv, VtB, mp2, out_aw, cvb);
    gemm_k<1><<<dim3(32, 8, 1), 256, 0, stream>>>(cvb, wt + 3 * 262144, bo, bo, bo, out_cv, (unsigned short*)nullptr);
}

// Round 17
// 115.991 us; speedup vs baseline: 1.0456x; 1.0456x over previous
//
#include <hip/hip_runtime.h>

typedef short sh8 __attribute__((ext_vector_type(8)));   // 8 bf16
typedef float fx4 __attribute__((ext_vector_type(4)));   // MFMA accumulator
typedef float fl4 __attribute__((ext_vector_type(4)));   // ext-vector float4
typedef unsigned short us4 __attribute__((ext_vector_type(4)));

__device__ __forceinline__ unsigned short f2bf(float f) {
    union { float f; unsigned u; } v; v.f = f;
    unsigned r = v.u + 0x7FFFu + ((v.u >> 16) & 1u);   // RNE
    return (unsigned short)(r >> 16);
}
__device__ __forceinline__ float EX2(float x) { return __builtin_amdgcn_exp2f(x); }
__device__ __forceinline__ unsigned cvtpk(float a, float b) {   // 2xf32 -> packed bf16 (RNE)
    unsigned r;
    asm("v_cvt_pk_bf16_f32 %0, %1, %2" : "=v"(r) : "v"(a), "v"(b));
    return r;
}
// async global->LDS, 16B per lane; LDS dest = wave-uniform base + lane*16
__device__ __forceinline__ void gl16(const unsigned short* g, unsigned short* l) {
    __builtin_amdgcn_global_load_lds(
        (const __attribute__((address_space(1))) unsigned int*)g,
        (__attribute__((address_space(3))) unsigned int*)l, 16, 0, 0);
}

// ---------------- prep: cvt inputs + transpose weights + pack mask (r9-proven) ------------
__global__ __launch_bounds__(256) void prep(const float* __restrict__ x0,
                                            const float* __restrict__ x1,
                                            const float* __restrict__ x2,
                                            const float* __restrict__ w0,
                                            const float* __restrict__ w1,
                                            const float* __restrict__ w2,
                                            const float* __restrict__ w3,
                                            const int* __restrict__ mask,
                                            unsigned short* __restrict__ in_bf,
                                            unsigned short* __restrict__ wt,
                                            unsigned long long* __restrict__ mp2) {
    __shared__ float tw[32][33];
    const int bid = blockIdx.x, tid = threadIdx.x;
    if (bid < 1536) {                               // cvt: 3 inputs x 512 blocks
        const int z = bid >> 9, xb = bid & 511;
        const float* src = z == 0 ? x0 : (z == 1 ? x1 : x2);
        unsigned short* dst = in_bf + (size_t)z * 2097152;
        for (int i = xb * 256 + tid; i < 524288; i += 131072) {
            float4 v = ((const float4*)src)[i];
            ushort4 o;
            o.x = f2bf(v.x); o.y = f2bf(v.y); o.z = f2bf(v.z); o.w = f2bf(v.w);
            ((ushort4*)dst)[i] = o;
        }
    } else if (bid < 2560) {                        // transpose_w: 4 x (16x16) blocks
        const int t = bid - 1536;
        const int z = t >> 8, bx = t & 15, by = (t >> 4) & 15;
        const float* W = z == 0 ? w0 : z == 1 ? w1 : z == 2 ? w2 : w3;
        unsigned short* Wt = wt + (size_t)z * 262144;
        const int tx = tid & 31, ty = tid >> 5;
        #pragma unroll
        for (int i = 0; i < 4; ++i)
            tw[ty + i * 8][tx] = W[(size_t)(by * 32 + ty + i * 8) * 512 + bx * 32 + tx];
        __syncthreads();
        #pragma unroll
        for (int i = 0; i < 4; ++i)
            Wt[(size_t)(bx * 32 + ty + i * 8) * 512 + by * 32 + tx] = f2bf(tw[tx][ty + i * 8]);
    } else {                                        // pack_mask: 16 blocks (2 b x 8)
        const int p = bid - 2560;
        const int b = p >> 3, k = (p & 7) * 256 + tid;
        int v = mask[(size_t)b * 4194304 + k];
        unsigned long long bal = __ballot(v != 0);
        if ((tid & 63) == 0) mp2[b * 32 + (k >> 6)] = bal;
    }
}

// ---------------- GEMM: C[4096,512] = A_bf16 @ Wt^T + bias (r9-proven) ----------------
template <int MODE>
__global__ __launch_bounds__(256) void gemm_k(const unsigned short* __restrict__ Aall,
                                              const unsigned short* __restrict__ Wtall,
                                              const float* __restrict__ b0,
                                              const float* __restrict__ b1,
                                              const float* __restrict__ b2,
                                              void* __restrict__ outp,
                                              unsigned short* __restrict__ VtB) {
    const int z = blockIdx.z;
    const unsigned short* A  = Aall  + (size_t)z * (4096 * 512);
    const unsigned short* Bt = Wtall + (size_t)z * (512 * 512);
    const float* bias = (MODE == 0) ? (z == 0 ? b0 : (z == 1 ? b1 : b2)) : b0;

    __shared__ __align__(16) unsigned short As[128 * 64];   // XOR-swizzled chunks
    __shared__ __align__(16) unsigned short Bs[64 * 64];

    const int tid = threadIdx.x;
    const int wid = tid >> 6, lane = tid & 63, lr = lane & 15, lg = lane >> 4;
    const int wr = wid >> 1, wc = wid & 1;
    const int mblk = blockIdx.x * 128, nblk = blockIdx.y * 64;
    const int r7 = lr & 7;

    fx4 acc[4][2];
    #pragma unroll
    for (int mf = 0; mf < 4; ++mf)
        #pragma unroll
        for (int nf = 0; nf < 2; ++nf)
            #pragma unroll
            for (int j = 0; j < 4; ++j) acc[mf][nf][j] = 0.f;

    for (int kt = 0; kt < 8; ++kt) {
        __syncthreads();                         // WAR
        #pragma unroll
        for (int g = 0; g < 4; ++g) {            // A: 1024 chunks, 256/wave
            int ci = wid * 256 + g * 64 + lane;
            int r = ci >> 3, c = (ci & 7) ^ (r & 7);
            gl16(A + (size_t)(mblk + r) * 512 + kt * 64 + c * 8, &As[(wid * 256 + g * 64) * 8]);
        }
        #pragma unroll
        for (int g = 0; g < 2; ++g) {            // B: 512 chunks, 128/wave
            int ci = wid * 128 + g * 64 + lane;
            int r = ci >> 3, c = (ci & 7) ^ (r & 7);
            gl16(Bt + (size_t)(nblk + r) * 512 + kt * 64 + c * 8, &Bs[(wid * 128 + g * 64) * 8]);
        }
        __syncthreads();                         // RAW (compiler drains vmcnt)
        #pragma unroll
        for (int d = 0; d < 2; ++d) {
            sh8 af[4], bf[2];
            #pragma unroll
            for (int mf = 0; mf < 4; ++mf)
                af[mf] = *(const sh8*)&As[(wr * 64 + mf * 16 + lr) * 64 + (((d * 4 + lg) ^ r7) * 8)];
            #pragma unroll
            for (int nf = 0; nf < 2; ++nf)
                bf[nf] = *(const sh8*)&Bs[(wc * 32 + nf * 16 + lr) * 64 + (((d * 4 + lg) ^ r7) * 8)];
            #pragma unroll
            for (int mf = 0; mf < 4; ++mf)
                #pragma unroll
                for (int nf = 0; nf < 2; ++nf)
                    acc[mf][nf] = __builtin_amdgcn_mfma_f32_16x16x32_bf16(af[mf], bf[nf], acc[mf][nf], 0, 0, 0);
        }
    }

    if (MODE == 0 && z == 1) {
        // V: write transposed only -> VtB[(b*8+h)*64 + dd][lq]
        #pragma unroll
        for (int nf = 0; nf < 2; ++nf) {
            int n = nblk + wc * 32 + nf * 16 + lr;
            float bv = bias[n];
            int h = n >> 6, dd = n & 63;
            #pragma unroll
            for (int mf = 0; mf < 4; ++mf) {
                int m0 = mblk + wr * 64 + mf * 16 + lg * 4;
                int bb = m0 >> 11, lq = m0 & 2047;
                ushort4 o;
                o.x = f2bf(acc[mf][nf][0] + bv);
                o.y = f2bf(acc[mf][nf][1] + bv);
                o.z = f2bf(acc[mf][nf][2] + bv);
                o.w = f2bf(acc[mf][nf][3] + bv);
                *(ushort4*)(VtB + ((size_t)(bb * 8 + h) * 64 + dd) * 2048 + lq) = o;
            }
        }
    } else {
        #pragma unroll
        for (int nf = 0; nf < 2; ++nf) {
            int n = nblk + wc * 32 + nf * 16 + lr;
            float bv = bias[n];
            #pragma unroll
            for (int mf = 0; mf < 4; ++mf) {
                #pragma unroll
                for (int j = 0; j < 4; ++j) {
                    int m = mblk + wr * 64 + mf * 16 + lg * 4 + j;
                    float val = acc[mf][nf][j] + bv;
                    if (MODE == 0) {
                        if (z == 2) val *= 0.180336880f;   // (1/sqrt(64))*log2e: exp2 domain
                        int bb = m >> 11, lq = m & 2047, h = n >> 6, dd = n & 63;
                        ((unsigned short*)outp)[(size_t)(((z * 2 + bb) * 8 + h) * 2048 + lq) * 64 + dd] = f2bf(val);
                    } else {
                        ((float*)outp)[(size_t)m * 512 + n] = val;
                    }
                }
            }
        }
    }
}

// ---------------- fused attention: pair-granularity pipeline (2 tiles / barrier pair) -----
__device__ __forceinline__ void stage_k1(const unsigned short* Kg, unsigned short* sK,
                                         int t, int w, int lane) {
    #pragma unroll
    for (int g = 0; g < 2; ++g) {
        int ci = w * 128 + g * 64 + lane;
        int r = ci >> 3, c = (ci & 7) ^ (r & 7);
        gl16(Kg + (size_t)(t * 64 + r) * 64 + c * 8, sK + (w * 128 + g * 64) * 8);
    }
}
__device__ __forceinline__ void stage_kv(const unsigned short* Kg, const unsigned short* Vg,
                                         unsigned short* sK, unsigned short* sV,
                                         int t, int w, int lane) {
    #pragma unroll
    for (int g = 0; g < 2; ++g) {
        int ci = w * 128 + g * 64 + lane;
        int r = ci >> 3, c = (ci & 7) ^ (r & 7);
        gl16(Kg + (size_t)(t * 64 + r) * 64 + c * 8, sK + (w * 128 + g * 64) * 8);
        gl16(Vg + (size_t)r * 2048 + t * 64 + c * 8, sV + (w * 128 + g * 64) * 8);
    }
}

__global__ __launch_bounds__(256, 2) void attn_fused(const unsigned short* __restrict__ qkv,
                                                     const unsigned short* __restrict__ Vt,
                                                     const unsigned long long* __restrict__ mp2,
                                                     float* __restrict__ aw,
                                                     unsigned short* __restrict__ cv) {
    const int bid = blockIdx.x;
    // batch-balanced XCD swizzle: XCD c hosts bh {c, c+8} (one per batch), bijective.
    const int bh = (bid & 7) | (((bid >> 3) & 1) << 3);
    const int qb = bid >> 4;
    const int b = bh >> 3, h = bh & 7;
    const unsigned short* Kg = qkv + (size_t)bh * 131072;
    const unsigned short* Vg = Vt + (size_t)bh * 131072;    // [64 d][2048 k]
    const unsigned short* Qg = qkv + 2 * 2097152 + (size_t)bh * 131072 + (size_t)qb * 4096;

    // KR[0..3]: K 4-slot ring (tile kt -> slot kt&3); KR[4..7]: V slots (phase B)
    __shared__ __align__(16) unsigned short KR[8][4096];
    __shared__ __align__(16) unsigned short Pb[4096];

    const int tid = threadIdx.x, w = tid >> 6, lane = tid & 63, lr = lane & 15, lg = lane >> 4;
    const int r7 = lr & 7;
    const int q = qb * 64 + w * 16 + lr;

    sh8 qf0 = *(const sh8*)(Qg + (w * 16 + lr) * 64 + lg * 8);
    sh8 qf1 = *(const sh8*)(Qg + (w * 16 + lr) * 64 + 32 + lg * 8);
    unsigned long long mwv = (lane < 32) ? mp2[b * 32 + lane] : 0ull;

    // trailing-masked-tile count (block-uniform: mask depends only on b)
    unsigned long long bits = __ballot(mwv != 0ull);
    const int ntiles = (bits == 0ull) ? 0 : (64 - __clzll(bits));
    const int npairs = (ntiles + 1) >> 1;

    float* awb = aw + (size_t)bh * 4194304 + (size_t)q * 2048;

    // ---------- phase A: softmax stats (exp2 domain), 2 tiles per barrier pair ------------
    float m_ = -3e38f, l_ = 0.f;
    if (ntiles > 0) {
        asm volatile("s_waitcnt vmcnt(0)" ::: "memory");
        stage_k1(Kg, KR[0], 0, w, lane);
        stage_k1(Kg, KR[1], 1, w, lane);
        if (npairs > 1) {
            stage_k1(Kg, KR[2], 2, w, lane);
            stage_k1(Kg, KR[3], 3, w, lane);
        }
        for (int p = 0; p < npairs; ++p) {
            if (p >= 1 && p <= npairs - 2) {
                stage_k1(Kg, KR[(2 * p + 2) & 3], 2 * p + 2, w, lane);
                stage_k1(Kg, KR[(2 * p + 3) & 3], 2 * p + 3, w, lane);
            }
            if (p == npairs - 1) asm volatile("s_waitcnt vmcnt(0)" ::: "memory");
            else                 asm volatile("s_waitcnt vmcnt(4)" ::: "memory");
            asm volatile("s_barrier" ::: "memory");          // RAW: pair p staged
            #pragma unroll
            for (int tt = 0; tt < 2; ++tt) {
                const int kt = 2 * p + tt;
                unsigned long long mw = __shfl(mwv, kt, 64);
                if (mw == 0ull) continue;
                const unsigned short* KsB = KR[kt & 3];
                fx4 accs[4];
                #pragma unroll
                for (int mt = 0; mt < 4; ++mt) {
                    sh8 kf0 = *(const sh8*)&KsB[(mt * 16 + lr) * 64 + ((lg ^ r7) * 8)];
                    sh8 kf1 = *(const sh8*)&KsB[(mt * 16 + lr) * 64 + (((4 + lg) ^ r7) * 8)];
                    fx4 zz; zz[0] = 0.f; zz[1] = 0.f; zz[2] = 0.f; zz[3] = 0.f;
                    zz = __builtin_amdgcn_mfma_f32_16x16x32_bf16(kf0, qf0, zz, 0, 0, 0);
                    accs[mt] = __builtin_amdgcn_mfma_f32_16x16x32_bf16(kf1, qf1, zz, 0, 0, 0);
                }
                float sv[16], tmax = -3e38f;
                if (mw == ~0ull) {
                    #pragma unroll
                    for (int mt = 0; mt < 4; ++mt)
                        #pragma unroll
                        for (int j = 0; j < 4; ++j) {
                            float s = accs[mt][j];
                            sv[mt * 4 + j] = s; tmax = fmaxf(tmax, s);
                        }
                } else {
                    #pragma unroll
                    for (int mt = 0; mt < 4; ++mt)
                        #pragma unroll
                        for (int j = 0; j < 4; ++j) {
                            int kl = mt * 16 + lg * 4 + j;
                            bool ok = (mw >> kl) & 1ull;
                            float s = ok ? accs[mt][j] : -3e38f;
                            sv[mt * 4 + j] = s; tmax = fmaxf(tmax, s);
                        }
                }
                float mnew = fmaxf(m_, tmax);
                float ps = 0.f;
                #pragma unroll
                for (int i = 0; i < 16; ++i) ps += EX2(sv[i] - mnew);
                l_ = l_ * EX2(m_ - mnew) + ps;
                m_ = mnew;
            }
            asm volatile("s_barrier" ::: "memory");          // WAR: slots free
        }
    }
    // butterfly merge across lg groups -> every lane holds full-row (M, L)
    #pragma unroll
    for (int off = 16; off <= 32; off <<= 1) {
        float mo = __shfl_xor(m_, off), lo = __shfl_xor(l_, off);
        float mn = fmaxf(m_, mo);
        l_ = l_ * EX2(m_ - mn) + lo * EX2(mo - mn);
        m_ = mn;
    }
    // fold 1/L into the exponent: p = 2^(s - Mshift), Mshift = M + log2(L)
    const float Mshift = (l_ > 0.f) ? (m_ + __log2f(l_)) : 3e38f;

    // ---------- phase B: recompute S^T, write normalized aw, accumulate PV ----------
    fx4 acco[4];
    #pragma unroll
    for (int md = 0; md < 4; ++md) { acco[md][0] = 0.f; acco[md][1] = 0.f; acco[md][2] = 0.f; acco[md][3] = 0.f; }

    if (ntiles > 0) {
        asm volatile("s_waitcnt vmcnt(0)" ::: "memory");
        stage_kv(Kg, Vg, KR[0], KR[4], 0, w, lane);
        stage_kv(Kg, Vg, KR[1], KR[5], 1, w, lane);
        if (npairs > 1) {
            stage_kv(Kg, Vg, KR[2], KR[6], 2, w, lane);
            stage_kv(Kg, Vg, KR[3], KR[7], 3, w, lane);
        }
        for (int p = 0; p < npairs; ++p) {
            if (p >= 1 && p <= npairs - 2) {
                stage_kv(Kg, Vg, KR[(2 * p + 2) & 3], KR[4 + ((2 * p + 2) & 3)], 2 * p + 2, w, lane);
                stage_kv(Kg, Vg, KR[(2 * p + 3) & 3], KR[4 + ((2 * p + 3) & 3)], 2 * p + 3, w, lane);
            }
            // FIFO (steady): [L_p 8][S_{p-1} 8][L_{p+1} 8] -> vmcnt(16) retires L_p only.
            if (p == 0 && npairs == 1) asm volatile("s_waitcnt vmcnt(0)" ::: "memory");
            else if (p == 0 || p == npairs - 1) asm volatile("s_waitcnt vmcnt(8)" ::: "memory");
            else                                asm volatile("s_waitcnt vmcnt(16)" ::: "memory");
            asm volatile("s_barrier" ::: "memory");          // RAW

            #pragma unroll
            for (int tt = 0; tt < 2; ++tt) {
                const int kt = 2 * p + tt;
                unsigned long long mw = __shfl(mwv, kt, 64);
                const unsigned short* KsB = KR[kt & 3];
                const unsigned short* VsB = KR[4 + (kt & 3)];

                if (mw != 0ull) {
                    fx4 accs[4];
                    #pragma unroll
                    for (int mt = 0; mt < 4; ++mt) {
                        sh8 kf0 = *(const sh8*)&KsB[(mt * 16 + lr) * 64 + ((lg ^ r7) * 8)];
                        sh8 kf1 = *(const sh8*)&KsB[(mt * 16 + lr) * 64 + (((4 + lg) ^ r7) * 8)];
                        fx4 zz; zz[0] = 0.f; zz[1] = 0.f; zz[2] = 0.f; zz[3] = 0.f;
                        zz = __builtin_amdgcn_mfma_f32_16x16x32_bf16(kf0, qf0, zz, 0, 0, 0);
                        accs[mt] = __builtin_amdgcn_mfma_f32_16x16x32_bf16(kf1, qf1, zz, 0, 0, 0);
                    }
                    bool full = (mw == ~0ull);
                    #pragma unroll
                    for (int mt = 0; mt < 4; ++mt) {
                        fl4 pw;
                        #pragma unroll
                        for (int j = 0; j < 4; ++j) {
                            int kl = mt * 16 + lg * 4 + j;
                            bool ok = full || ((mw >> kl) & 1ull);
                            pw[j] = EX2((ok ? accs[mt][j] : -3e38f) - Mshift);
                        }
                        *(fl4*)(awb + kt * 64 + mt * 16 + lg * 4) = pw;
                        int sc = (mt * 2 + (lg >> 1)) ^ r7;
                        *(uint2*)&Pb[(w * 16 + lr) * 64 + sc * 8 + (lg & 1) * 4] =
                            make_uint2(cvtpk(pw[0], pw[1]), cvtpk(pw[2], pw[3]));
                    }
                    asm volatile("s_waitcnt lgkmcnt(0)" ::: "memory");   // wave-private Pb RAW
                    __builtin_amdgcn_sched_barrier(0);
                    sh8 bp0 = *(const sh8*)&Pb[(w * 16 + lr) * 64 + ((lg ^ r7) * 8)];
                    sh8 bp1 = *(const sh8*)&Pb[(w * 16 + lr) * 64 + (((4 + lg) ^ r7) * 8)];
                    #pragma unroll
                    for (int md = 0; md < 4; ++md) {
                        sh8 vf0 = *(const sh8*)&VsB[(md * 16 + lr) * 64 + ((lg ^ r7) * 8)];
                        sh8 vf1 = *(const sh8*)&VsB[(md * 16 + lr) * 64 + (((4 + lg) ^ r7) * 8)];
                        acco[md] = __builtin_amdgcn_mfma_f32_16x16x32_bf16(vf0, bp0, acco[md], 0, 0, 0);
                        acco[md] = __builtin_amdgcn_mfma_f32_16x16x32_bf16(vf1, bp1, acco[md], 0, 0, 0);
                    }
                } else {
                    fl4 z4 = {0.f, 0.f, 0.f, 0.f};
                    #pragma unroll
                    for (int mt = 0; mt < 4; ++mt)      // exactly 4 stores: keeps vmcnt accounting
                        *(fl4*)(awb + kt * 64 + mt * 16 + lg * 4) = z4;
                }
            }
            asm volatile("s_barrier" ::: "memory");          // WAR before restage
        }
    }

    // zero-fill trailing fully-masked tiles (no staging, no barriers)
    for (int kt = ntiles; kt < 32; ++kt) {
        fl4 z4 = {0.f, 0.f, 0.f, 0.f};
        #pragma unroll
        for (int mt = 0; mt < 4; ++mt)
            *(fl4*)(awb + kt * 64 + mt * 16 + lg * 4) = z4;
    }

    // epilogue: complete PV row -> cvb bf16 [4096][512]
    #pragma unroll
    for (int md = 0; md < 4; ++md) {
        uint2 o = make_uint2(cvtpk(acco[md][0], acco[md][1]), cvtpk(acco[md][2], acco[md][3]));
        *(uint2*)(cv + (size_t)(b * 2048 + q) * 512 + h * 64 + md * 16 + lg * 4) = o;
    }
}

// ---------------- launch ----------------
extern "C" void kernel_launch(void* const* d_in, const int* in_sizes, int n_in,
                              void* d_out, int out_size, void* d_ws, size_t ws_size,
                              hipStream_t stream) {
    const float* key_in   = (const float*)d_in[0];
    const float* value_in = (const float*)d_in[1];
    const float* query_in = (const float*)d_in[2];
    const float* Wk = (const float*)d_in[3];
    const float* bk = (const float*)d_in[4];
    const float* Wv = (const float*)d_in[5];
    const float* bv = (const float*)d_in[6];
    const float* Wq = (const float*)d_in[7];
    const float* bq = (const float*)d_in[8];
    const float* Wo = (const float*)d_in[9];
    const float* bo = (const float*)d_in[10];
    const int* mask = (const int*)d_in[11];

    char* ws = (char*)d_ws;
    unsigned short* in_bf = (unsigned short*)(ws);                  // 12.58M
    unsigned short* qkv   = (unsigned short*)(ws + 12582912);       // 12.58M: K slot0, Q slot2
    unsigned short* cvb   = (unsigned short*)(ws + 12582912 + 4194304); // overlays unused V slot1
    unsigned short* wt    = (unsigned short*)(ws + 25165824);       // 2.10M
    unsigned short* VtB   = (unsigned short*)(ws + 27262976);       // 4.19M
    unsigned long long* mp2 = (unsigned long long*)(ws + 31457280); // 512 B

    float* out_cv = (float*)d_out;
    float* out_aw = (float*)d_out + 2097152;

    prep<<<dim3(2576), 256, 0, stream>>>(key_in, value_in, query_in,
                                         Wk, Wv, Wq, Wo, mask, in_bf, wt, mp2);
    gemm_k<0><<<dim3(32, 8, 3), 256, 0, stream>>>(in_bf, wt, bk, bv, bq, qkv, VtB);
    attn_fused<<<dim3(512), 256, 0, stream>>>(qkv, VtB, mp2, out_aw, cvb);
    gemm_k<1><<<dim3(32, 8, 1), 256, 0, stream>>>(cvb, wt + 3 * 262144, bo, bo, bo, out_cv, (unsigned short*)nullptr);
}